// Round 20
// baseline (143.799 us; speedup 1.0000x reference)
//
#include <hip/hip_runtime.h>
#include <hip/hip_bf16.h>
#include <stdint.h>

// Problem constants: B=2, N=2048, D=1024, H=16, head dim s=64.
// Global I/O fp32; internal X/W/Q/K/V/Y intermediates bf16 in d_ws.
// Q is pre-scaled by 0.125*log2e so attention softmax runs in exp2 domain.
#define BB 2
#define NN 2048
#define DD 1024
#define HH 16
#define SS 64

typedef short short8 __attribute__((ext_vector_type(8)));
typedef float f32x4 __attribute__((ext_vector_type(4)));

__device__ __forceinline__ float bf2f(uint16_t u) {
    return __uint_as_float(((uint32_t)u) << 16);
}
__device__ __forceinline__ uint16_t f2bf(float f) {
    uint32_t u = __float_as_uint(f);
    return (uint16_t)((u + 0x7FFFu + ((u >> 16) & 1u)) >> 16);  // RNE
}
__device__ __forceinline__ short8 cvt8(float4 a, float4 b) {
    short8 s;
    s[0] = (short)f2bf(a.x); s[1] = (short)f2bf(a.y);
    s[2] = (short)f2bf(a.z); s[3] = (short)f2bf(a.w);
    s[4] = (short)f2bf(b.x); s[5] = (short)f2bf(b.y);
    s[6] = (short)f2bf(b.z); s[7] = (short)f2bf(b.w);
    return s;
}

__device__ __forceinline__ void load_lds16(const uint16_t* g, uint16_t* l) {
    __builtin_amdgcn_global_load_lds(
        (const __attribute__((address_space(1))) void*)g,
        (__attribute__((address_space(3))) void*)l, 16, 0, 0);
}

#define XE  (4096 * 1024)
#define WQE (3072 * 1024)
#define WOE (1024 * 1024)

// ======================= fused fp32 -> bf16 bulk convert =======================
__global__ __launch_bounds__(256) void cvt_all(
    const float* __restrict__ x, const float* __restrict__ wq,
    const float* __restrict__ wo, uint16_t* __restrict__ dst)
{
    int i = (blockIdx.x * 256 + threadIdx.x) * 8;
    const float* src;
    int off;
    if (i < XE)            { src = x;  off = i; }
    else if (i < XE + WQE) { src = wq; off = i - XE; }
    else                   { src = wo; off = i - XE - WQE; }
    float4 a = *(const float4*)(src + off);
    float4 b = *(const float4*)(src + off + 4);
    *(short8*)(dst + i) = cvt8(a, b);
}

// ======================= QKV projection (MFMA, bf16 in) =======================
// C[4096,3072] = X[4096,1024] @ Wqkv[3072,1024]^T + bqkv
// -> Q bf16 (x0.125*log2e) [bh][2048][64], K bf16 [bh][2048][64], V^T [bh][64][2048]
// BK=64 + XCD swizzle (unchanged from round 15).
__global__ __launch_bounds__(256) void gemm_qkv(
    const uint16_t* __restrict__ X, const uint16_t* __restrict__ W,
    const float* __restrict__ bias,
    uint16_t* __restrict__ Qb, uint16_t* __restrict__ Kb, uint16_t* __restrict__ Vt)
{
    __shared__ __align__(16) uint16_t smem[18432];   // 36,864 B
    uint16_t* As0 = smem;            // [128][32]
    uint16_t* As1 = smem + 4096;
    uint16_t* Bs0 = smem + 8192;
    uint16_t* Bs1 = smem + 12288;

    const int tid = threadIdx.x;
    const int w = tid >> 6, l = tid & 63;
    const int lq = l & 15, lg = l >> 4;
    const int wm = w >> 1, wn = w & 1;

    const int flat = blockIdx.x + blockIdx.y * 24;
    const int xcd = flat & 7, g = flat >> 3;
    const int n0 = (xcd * 3 + (g % 3)) * 128;
    const int m0 = (g / 3) * 128;

    f32x4 acc[4][4] = {};

    for (int k0 = 0; k0 < 1024; k0 += 64) {
        __syncthreads();
        #pragma unroll
        for (int j = 0; j < 2; ++j) {
            const int c = (j * 4 + w) * 64 + l;
            const size_t ra = (size_t)(m0 + (c >> 2)) * 1024 + k0 + (c & 3) * 8;
            const size_t rb = (size_t)(n0 + (c >> 2)) * 1024 + k0 + (c & 3) * 8;
            load_lds16(X + ra,      As0 + (j * 4 + w) * 512);
            load_lds16(X + ra + 32, As1 + (j * 4 + w) * 512);
            load_lds16(W + rb,      Bs0 + (j * 4 + w) * 512);
            load_lds16(W + rb + 32, Bs1 + (j * 4 + w) * 512);
        }
        __syncthreads();
        short8 af[4], bfr[4];
        #pragma unroll
        for (int mi = 0; mi < 4; ++mi)
            af[mi] = *(const short8*)&As0[(wm * 64 + mi * 16 + lq) * 32 + lg * 8];
        #pragma unroll
        for (int ni = 0; ni < 4; ++ni)
            bfr[ni] = *(const short8*)&Bs0[(wn * 64 + ni * 16 + lq) * 32 + lg * 8];
        #pragma unroll
        for (int mi = 0; mi < 4; ++mi)
            #pragma unroll
            for (int ni = 0; ni < 4; ++ni)
                acc[mi][ni] = __builtin_amdgcn_mfma_f32_16x16x32_bf16(
                    af[mi], bfr[ni], acc[mi][ni], 0, 0, 0);
        #pragma unroll
        for (int mi = 0; mi < 4; ++mi)
            af[mi] = *(const short8*)&As1[(wm * 64 + mi * 16 + lq) * 32 + lg * 8];
        #pragma unroll
        for (int ni = 0; ni < 4; ++ni)
            bfr[ni] = *(const short8*)&Bs1[(wn * 64 + ni * 16 + lq) * 32 + lg * 8];
        #pragma unroll
        for (int mi = 0; mi < 4; ++mi)
            #pragma unroll
            for (int ni = 0; ni < 4; ++ni)
                acc[mi][ni] = __builtin_amdgcn_mfma_f32_16x16x32_bf16(
                    af[mi], bfr[ni], acc[mi][ni], 0, 0, 0);
    }

    // ---------------- epilogue: bf16 scatter via LDS transpose ----------------
    __syncthreads();
    const int part = n0 >> 10;
    const int hh = ((n0 + wn * 64) & 1023) >> 6;
    const int mrow0 = m0 + wm * 64;
    const int bh = (mrow0 >> 11) * 16 + hh;
    const int tok0 = mrow0 & 2047;
    const float scl = (part == 0) ? 0.125f * 1.44269504089f : 1.0f;

    float bias4[4];
    #pragma unroll
    for (int ni = 0; ni < 4; ++ni)
        bias4[ni] = bias[n0 + wn * 64 + ni * 16 + lq];

    uint16_t* T = smem + w * 4608;                   // [64][72] bf16, wave-private
    if (part < 2) {
        #pragma unroll
        for (int mi = 0; mi < 4; ++mi)
            #pragma unroll
            for (int ni = 0; ni < 4; ++ni)
                #pragma unroll
                for (int r = 0; r < 4; ++r)
                    T[(mi * 16 + lg * 4 + r) * 72 + ni * 16 + lq] =
                        f2bf((acc[mi][ni][r] + bias4[ni]) * scl);
    } else {
        #pragma unroll
        for (int mi = 0; mi < 4; ++mi)
            #pragma unroll
            for (int ni = 0; ni < 4; ++ni)
                #pragma unroll
                for (int r = 0; r < 4; ++r)
                    T[(ni * 16 + lq) * 72 + mi * 16 + lg * 4 + r] =
                        f2bf(acc[mi][ni][r] + bias4[ni]);
    }

    const int a0 = l >> 3, b8 = (l & 7) * 8;
    #pragma unroll
    for (int i = 0; i < 8; ++i) {
        int a = i * 8 + a0;
        short8 u = *(short8*)&T[a * 72 + b8];
        uint16_t* p;
        if (part < 2) {
            uint16_t* dst = (part == 0) ? Qb : Kb;
            p = dst + ((size_t)bh * 2048 + tok0 + a) * 64 + b8;
        } else {
            p = Vt + ((size_t)bh * 64 + a) * 2048 + tok0 + b8;
        }
        *(short8*)p = u;
    }
}

// ======================= MFMA flash attention (64 q-rows, 4-way kv-split) =======
// 1024 blocks x 256 thr (4 waves). All waves share the block's 64 q-rows; wave
// w owns kv tiles kt === w (mod 4) -> the straggler block's serial chain halves
// (16 -> 8 wave-steps), which r19 showed IS the makespan. Exact guarded tree
// merge in LDS: waves{1,3} post -> {0,2} merge; wave2 posts -> wave0 finalizes.
// Guard w = (l==0) ? 0 : exp2(m-mx) makes empty-wave partials exact no-ops.
__device__ __forceinline__ void loadK8(const uint16_t* kp, short8 (&d)[8]) {
    #pragma unroll
    for (int n = 0; n < 4; ++n) {
        d[2 * n]     = *(const short8*)(kp + n * 1024);
        d[2 * n + 1] = *(const short8*)(kp + n * 1024 + 32);
    }
}
__device__ __forceinline__ void loadV8(const uint16_t* vp, short8 (&d)[8]) {
    #pragma unroll
    for (int n = 0; n < 4; ++n) {
        d[2 * n]     = *(const short8*)(vp + n * 32768);
        d[2 * n + 1] = *(const short8*)(vp + n * 32768 + 32);
    }
}

#define DEFER_THR 11.5f   // ~8 nats in log2 units

__global__ __launch_bounds__(256) void attn_mfma(
    const uint16_t* __restrict__ Q, const uint16_t* __restrict__ K,
    const uint16_t* __restrict__ Vt, uint16_t* __restrict__ Y)
{
    const int id = blockIdx.x;
    const int bh = id & 31;               // id%8 -> stable XCD per bh group
    const int blk = 31 - (id >> 5);       // 64-row q-block, heaviest first
    const int qt = blk;                   // last kv tile index
    const int q0 = blk * 64;

    const int wv = threadIdx.x >> 6;      // kv residue class this wave owns (0..3)
    const int lane = threadIdx.x & 63;
    const int lq = lane & 15;
    const int lg = lane >> 4;

    __shared__ __align__(16) uint16_t Pl[4][2][16][72];  // [wave][pair-slot]
    __shared__ float  Yreg[2][64][68];                   // merge y regions (padded)
    __shared__ float2 MLreg[2][64];                      // merge (m, l) regions

    const uint16_t* Kb = K + (size_t)bh * (2048 * 64);
    const uint16_t* Vb = Vt + (size_t)bh * (64 * 2048);
    const int b = bh >> 4, h = bh & 15;

    short8 qf[4][2];
    #pragma unroll
    for (int sub = 0; sub < 4; ++sub) {
        const uint16_t* qb = Q + ((size_t)bh * 2048 + q0 + sub * 16 + lq) * 64 + lg * 8;
        qf[sub][0] = *(const short8*)qb;
        qf[sub][1] = *(const short8*)(qb + 32);
    }

    f32x4 y[4][4] = {};
    float m[4]    = {-INFINITY, -INFINITY, -INFINITY, -INFINITY};
    float lsum[4] = {0.f, 0.f, 0.f, 0.f};

    const uint16_t* kp = Kb + ((size_t)(wv * 64 + lq)) * 64 + lg * 8;
    const uint16_t* vp = Vb + (size_t)lq * 2048 + wv * 64 + lg * 8;

    short8 kf[8], vv[8];

    auto qkpair = [&](f32x4 (&z)[2][4], int s0) {
        __builtin_amdgcn_s_setprio(1);
        #pragma unroll
        for (int p = 0; p < 2; ++p)
            #pragma unroll
            for (int n = 0; n < 4; ++n) {
                f32x4 t = {};
                t = __builtin_amdgcn_mfma_f32_16x16x32_bf16(kf[2 * n], qf[s0 + p][0], t, 0, 0, 0);
                z[p][n] = __builtin_amdgcn_mfma_f32_16x16x32_bf16(kf[2 * n + 1], qf[s0 + p][1], t, 0, 0, 0);
            }
        __builtin_amdgcn_s_setprio(0);
    };

    auto smpv = [&](f32x4 (&z)[2][4], int s0, int kv0, bool domask) {
        if (domask) {
            #pragma unroll
            for (int p = 0; p < 2; ++p) {
                const int qrow = q0 + (s0 + p) * 16 + lq;
                #pragma unroll
                for (int n = 0; n < 4; ++n) {
                    const int kvb = kv0 + n * 16 + lg * 4;
                    #pragma unroll
                    for (int r = 0; r < 4; ++r)
                        if (kvb + r > qrow) z[p][n][r] = -INFINITY;
                }
            }
        }
        float mt[2];
        #pragma unroll
        for (int p = 0; p < 2; ++p) {
            float t = -INFINITY;
            #pragma unroll
            for (int n = 0; n < 4; ++n)
                #pragma unroll
                for (int r = 0; r < 4; ++r)
                    t = fmaxf(t, z[p][n][r]);
            mt[p] = t;
        }
        const float g = fmaxf(mt[0] - m[s0], mt[1] - m[s0 + 1]);
        const bool skip = __all(g <= DEFER_THR);
        if (!skip) {
            #pragma unroll
            for (int p = 0; p < 2; ++p) {
                const int s = s0 + p;
                float mf = fmaxf(mt[p], __shfl_xor(mt[p], 16));
                mf = fmaxf(mf, __shfl_xor(mf, 32));
                const float mn = fmaxf(m[s], mf);
                const float sc = exp2f(m[s] - mn);
                m[s] = mn;
                lsum[s] *= sc;
                float scy[4];
                #pragma unroll
                for (int r = 0; r < 4; ++r) scy[r] = __shfl(sc, lg * 4 + r);
                #pragma unroll
                for (int n = 0; n < 4; ++n)
                    #pragma unroll
                    for (int r = 0; r < 4; ++r)
                        y[s][n][r] *= scy[r];
            }
        }
        float ps[2] = {0.f, 0.f};
        #pragma unroll
        for (int p = 0; p < 2; ++p) {
            const int s = s0 + p;
            #pragma unroll
            for (int n = 0; n < 4; ++n) {
                float e0 = exp2f(z[p][n][0] - m[s]);
                float e1 = exp2f(z[p][n][1] - m[s]);
                float e2 = exp2f(z[p][n][2] - m[s]);
                float e3 = exp2f(z[p][n][3] - m[s]);
                ps[p] += (e0 + e1) + (e2 + e3);
                uint32_t p0, p1;
                asm("v_cvt_pk_bf16_f32 %0, %1, %2" : "=v"(p0) : "v"(e0), "v"(e1));
                asm("v_cvt_pk_bf16_f32 %0, %1, %2" : "=v"(p1) : "v"(e2), "v"(e3));
                uint2 u; u.x = p0; u.y = p1;
                *(uint2*)&Pl[wv][p][lq][n * 16 + lg * 4] = u;
            }
        }
        lsum[s0] += ps[0];
        lsum[s0 + 1] += ps[1];

        short8 pa[2][2];
        #pragma unroll
        for (int p = 0; p < 2; ++p) {
            pa[p][0] = *(short8*)&Pl[wv][p][lq][lg * 8];
            pa[p][1] = *(short8*)&Pl[wv][p][lq][lg * 8 + 32];
        }
        __builtin_amdgcn_s_setprio(1);
        #pragma unroll
        for (int p = 0; p < 2; ++p) {
            const int s = s0 + p;
            #pragma unroll
            for (int n = 0; n < 4; ++n) {
                y[s][n] = __builtin_amdgcn_mfma_f32_16x16x32_bf16(pa[p][0], vv[2 * n], y[s][n], 0, 0, 0);
                y[s][n] = __builtin_amdgcn_mfma_f32_16x16x32_bf16(pa[p][1], vv[2 * n + 1], y[s][n], 0, 0, 0);
            }
        }
        __builtin_amdgcn_s_setprio(0);
    };

    if (wv <= qt) {
        loadK8(kp, kf);
        int kt = wv;
        while (true) {
            const bool last = (kt + 4 > qt);
            const bool domask = (kt == qt);
            const int kv0 = kt * 64;
            loadV8(vp, vv);
            f32x4 z[2][4];
            qkpair(z, 0);
            smpv(z, 0, kv0, domask);
            qkpair(z, 2);
            if (!last) loadK8(kp + 16384, kf);   // next owned tile (kt+4)
            smpv(z, 2, kv0, domask);
            if (last) break;
            kp += 16384; vp += 256; kt += 4;
        }
    }

    // ---- reduce per-lane lsum across lg groups ----
    float ls[4];
    #pragma unroll
    for (int s = 0; s < 4; ++s) {
        float t = lsum[s];
        t += __shfl_xor(t, 16);
        t += __shfl_xor(t, 32);
        ls[s] = t;
    }

    // ---- guarded un-normalized merge helper (per sub-strip s) ----
    // own (m[s], ls[s], y[s]) <- merge with LDS region reg.
    auto mergeFrom = [&](int reg) {
        #pragma unroll
        for (int s = 0; s < 4; ++s) {
            float2 o = MLreg[reg][s * 16 + lq];
            const float mo = o.x, lo = o.y;
            const float mx = fmaxf(m[s], mo);
            const float w0 = (ls[s] == 0.f) ? 0.f : exp2f(m[s] - mx);
            const float w1 = (lo == 0.f) ? 0.f : exp2f(mo - mx);
            const float ln = ls[s] * w0 + lo * w1;
            float w0r[4], w1r[4];
            #pragma unroll
            for (int r = 0; r < 4; ++r) {
                w0r[r] = __shfl(w0, lg * 4 + r);
                w1r[r] = __shfl(w1, lg * 4 + r);
            }
            #pragma unroll
            for (int n = 0; n < 4; ++n)
                #pragma unroll
                for (int r = 0; r < 4; ++r)
                    y[s][n][r] = y[s][n][r] * w0r[r] +
                                 Yreg[reg][s * 16 + lg * 4 + r][n * 16 + lq] * w1r[r];
            m[s] = mx;
            ls[s] = ln;
        }
    };
    auto postTo = [&](int reg) {
        #pragma unroll
        for (int s = 0; s < 4; ++s) {
            #pragma unroll
            for (int n = 0; n < 4; ++n)
                #pragma unroll
                for (int r = 0; r < 4; ++r)
                    Yreg[reg][s * 16 + lg * 4 + r][n * 16 + lq] = y[s][n][r];
            if (lg == 0) MLreg[reg][s * 16 + lq] = make_float2(m[s], ls[s]);
        }
    };

    // stage A: waves 1,3 post; waves 0,2 merge
    if (wv == 1) postTo(0);
    if (wv == 3) postTo(1);
    __syncthreads();
    if (wv == 0) mergeFrom(0);
    if (wv == 2) mergeFrom(1);
    __syncthreads();
    // stage B: wave 2 posts merged; wave 0 finalizes
    if (wv == 2) postTo(0);
    __syncthreads();
    if (wv == 0) {
        mergeFrom(0);
        #pragma unroll
        for (int s = 0; s < 4; ++s) {
            const float inv = 1.0f / ls[s];
            float invy[4];
            #pragma unroll
            for (int r = 0; r < 4; ++r) invy[r] = __shfl(inv, lg * 4 + r);
            #pragma unroll
            for (int r = 0; r < 4; ++r) {
                int token = b * 2048 + q0 + s * 16 + lg * 4 + r;
                uint16_t* yrow = Y + (size_t)token * 1024 + h * 64;
                #pragma unroll
                for (int n = 0; n < 4; ++n)
                    yrow[n * 16 + lq] = f2bf(y[s][n][r] * invy[r]);
            }
        }
    }
}

// ======================= output projection (MFMA, fp32 out) =======================
// out[4096,1024] = Y(bf16) @ Wo(bf16)^T + bo. BK=64 + XCD column affinity.
__global__ __launch_bounds__(256) void gemm_proj(
    const uint16_t* __restrict__ Yin, const uint16_t* __restrict__ W,
    const float* __restrict__ bias, float* __restrict__ out)
{
    __shared__ __align__(16) uint16_t smem[16384];   // 4 x [128][32] = 32 KB
    uint16_t* As0 = smem;
    uint16_t* As1 = smem + 4096;
    uint16_t* Bs0 = smem + 8192;
    uint16_t* Bs1 = smem + 12288;

    const int tid = threadIdx.x;
    const int w = tid >> 6, l = tid & 63;
    const int lq = l & 15, lg = l >> 4;
    const int wm = w >> 1, wn = w & 1;

    const int flat = blockIdx.x + blockIdx.y * 8;
    const int n0 = (flat & 7) * 128;
    const int m0 = (flat >> 3) * 128;

    f32x4 acc[4][4] = {};

    for (int k0 = 0; k0 < 1024; k0 += 64) {
        __syncthreads();
        #pragma unroll
        for (int j = 0; j < 2; ++j) {
            const int c = (j * 4 + w) * 64 + l;
            const size_t ra = (size_t)(m0 + (c >> 2)) * 1024 + k0 + (c & 3) * 8;
            const size_t rb = (size_t)(n0 + (c >> 2)) * 1024 + k0 + (c & 3) * 8;
            load_lds16(Yin + ra,      As0 + (j * 4 + w) * 512);
            load_lds16(Yin + ra + 32, As1 + (j * 4 + w) * 512);
            load_lds16(W + rb,        Bs0 + (j * 4 + w) * 512);
            load_lds16(W + rb + 32,   Bs1 + (j * 4 + w) * 512);
        }
        __syncthreads();
        short8 af[4], bfr[4];
        #pragma unroll
        for (int mi = 0; mi < 4; ++mi)
            af[mi] = *(const short8*)&As0[(wm * 64 + mi * 16 + lq) * 32 + lg * 8];
        #pragma unroll
        for (int ni = 0; ni < 4; ++ni)
            bfr[ni] = *(const short8*)&Bs0[(wn * 64 + ni * 16 + lq) * 32 + lg * 8];
        #pragma unroll
        for (int mi = 0; mi < 4; ++mi)
            #pragma unroll
            for (int ni = 0; ni < 4; ++ni)
                acc[mi][ni] = __builtin_amdgcn_mfma_f32_16x16x32_bf16(
                    af[mi], bfr[ni], acc[mi][ni], 0, 0, 0);
        #pragma unroll
        for (int mi = 0; mi < 4; ++mi)
            af[mi] = *(const short8*)&As1[(wm * 64 + mi * 16 + lq) * 32 + lg * 8];
        #pragma unroll
        for (int ni = 0; ni < 4; ++ni)
            bfr[ni] = *(const short8*)&Bs1[(wn * 64 + ni * 16 + lq) * 32 + lg * 8];
        #pragma unroll
        for (int mi = 0; mi < 4; ++mi)
            #pragma unroll
            for (int ni = 0; ni < 4; ++ni)
                acc[mi][ni] = __builtin_amdgcn_mfma_f32_16x16x32_bf16(
                    af[mi], bfr[ni], acc[mi][ni], 0, 0, 0);
    }

    const int mrow0 = m0 + wm * 64;
    const int ncol0 = n0 + wn * 64;
    float bias4[4];
    #pragma unroll
    for (int ni = 0; ni < 4; ++ni)
        bias4[ni] = bias[ncol0 + ni * 16 + lq];

    #pragma unroll
    for (int mi = 0; mi < 4; ++mi)
        #pragma unroll
        for (int r = 0; r < 4; ++r) {
            const size_t rowoff = (size_t)(mrow0 + mi * 16 + lg * 4 + r) * 1024;
            #pragma unroll
            for (int ni = 0; ni < 4; ++ni)
                out[rowoff + ncol0 + ni * 16 + lq] = acc[mi][ni][r] + bias4[ni];
        }
}

// ======================= launcher =======================

extern "C" void kernel_launch(void* const* d_in, const int* in_sizes, int n_in,
                              void* d_out, int out_size, void* d_ws, size_t ws_size,
                              hipStream_t stream) {
    const float* x    = (const float*)d_in[0];
    // d_in[1] (causal mask) applied structurally.
    const float* Wqkv = (const float*)d_in[2];
    const float* bqkv = (const float*)d_in[3];
    const float* Wo   = (const float*)d_in[4];
    const float* bo   = (const float*)d_in[5];

    const size_t QK = (size_t)BB * HH * NN * SS;  // 4,194,304

    uint16_t* Xb  = (uint16_t*)d_ws;
    uint16_t* Wqb = Xb + XE;
    uint16_t* Wob = Wqb + WQE;
    uint16_t* Qb  = Wob + WOE;
    uint16_t* Kb  = Qb + QK;
    uint16_t* Vt  = Kb + QK;
    uint16_t* Yb  = Vt + QK;

    cvt_all<<<(XE + WQE + WOE) / 8 / 256, 256, 0, stream>>>(x, Wqkv, Wo, Xb);
    gemm_qkv<<<dim3(24, 32), 256, 0, stream>>>(Xb, Wqb, bqkv, Qb, Kb, Vt);
    attn_mfma<<<1024, 256, 0, stream>>>(Qb, Kb, Vt, Yb);
    gemm_proj<<<dim3(8, 32), 256, 0, stream>>>(Yb, Wob, bo, (float*)d_out);
}

// Round 21
// 142.629 us; speedup vs baseline: 1.0082x; 1.0082x over previous
//
#include <hip/hip_runtime.h>
#include <hip/hip_bf16.h>
#include <stdint.h>

// Problem constants: B=2, N=2048, D=1024, H=16, head dim s=64.
// Global I/O fp32; internal X/W/Q/K/V/Y intermediates bf16 in d_ws.
// Q is pre-scaled by 0.125*log2e so attention softmax runs in exp2 domain.
#define BB 2
#define NN 2048
#define DD 1024
#define HH 16
#define SS 64

typedef short short8 __attribute__((ext_vector_type(8)));
typedef float f32x4 __attribute__((ext_vector_type(4)));

__device__ __forceinline__ float bf2f(uint16_t u) {
    return __uint_as_float(((uint32_t)u) << 16);
}
__device__ __forceinline__ uint16_t f2bf(float f) {
    uint32_t u = __float_as_uint(f);
    return (uint16_t)((u + 0x7FFFu + ((u >> 16) & 1u)) >> 16);  // RNE
}
__device__ __forceinline__ short8 cvt8(float4 a, float4 b) {
    short8 s;
    s[0] = (short)f2bf(a.x); s[1] = (short)f2bf(a.y);
    s[2] = (short)f2bf(a.z); s[3] = (short)f2bf(a.w);
    s[4] = (short)f2bf(b.x); s[5] = (short)f2bf(b.y);
    s[6] = (short)f2bf(b.z); s[7] = (short)f2bf(b.w);
    return s;
}

__device__ __forceinline__ void load_lds16(const uint16_t* g, uint16_t* l) {
    __builtin_amdgcn_global_load_lds(
        (const __attribute__((address_space(1))) void*)g,
        (__attribute__((address_space(3))) void*)l, 16, 0, 0);
}

#define XE  (4096 * 1024)
#define WQE (3072 * 1024)
#define WOE (1024 * 1024)

// ======================= fused fp32 -> bf16 bulk convert =======================
__global__ __launch_bounds__(256) void cvt_all(
    const float* __restrict__ x, const float* __restrict__ wq,
    const float* __restrict__ wo, uint16_t* __restrict__ dst)
{
    int i = (blockIdx.x * 256 + threadIdx.x) * 8;
    const float* src;
    int off;
    if (i < XE)            { src = x;  off = i; }
    else if (i < XE + WQE) { src = wq; off = i - XE; }
    else                   { src = wo; off = i - XE - WQE; }
    float4 a = *(const float4*)(src + off);
    float4 b = *(const float4*)(src + off + 4);
    *(short8*)(dst + i) = cvt8(a, b);
}

// ======================= QKV projection (MFMA, bf16 in) =======================
// C[4096,3072] = X[4096,1024] @ Wqkv[3072,1024]^T + bqkv
// -> Q bf16 (x0.125*log2e) [bh][2048][64], K bf16 [bh][2048][64], V^T [bh][64][2048]
// BK=64 + XCD swizzle (unchanged from round 15).
__global__ __launch_bounds__(256) void gemm_qkv(
    const uint16_t* __restrict__ X, const uint16_t* __restrict__ W,
    const float* __restrict__ bias,
    uint16_t* __restrict__ Qb, uint16_t* __restrict__ Kb, uint16_t* __restrict__ Vt)
{
    __shared__ __align__(16) uint16_t smem[18432];   // 36,864 B
    uint16_t* As0 = smem;            // [128][32]
    uint16_t* As1 = smem + 4096;
    uint16_t* Bs0 = smem + 8192;
    uint16_t* Bs1 = smem + 12288;

    const int tid = threadIdx.x;
    const int w = tid >> 6, l = tid & 63;
    const int lq = l & 15, lg = l >> 4;
    const int wm = w >> 1, wn = w & 1;

    const int flat = blockIdx.x + blockIdx.y * 24;
    const int xcd = flat & 7, g = flat >> 3;
    const int n0 = (xcd * 3 + (g % 3)) * 128;
    const int m0 = (g / 3) * 128;

    f32x4 acc[4][4] = {};

    for (int k0 = 0; k0 < 1024; k0 += 64) {
        __syncthreads();
        #pragma unroll
        for (int j = 0; j < 2; ++j) {
            const int c = (j * 4 + w) * 64 + l;
            const size_t ra = (size_t)(m0 + (c >> 2)) * 1024 + k0 + (c & 3) * 8;
            const size_t rb = (size_t)(n0 + (c >> 2)) * 1024 + k0 + (c & 3) * 8;
            load_lds16(X + ra,      As0 + (j * 4 + w) * 512);
            load_lds16(X + ra + 32, As1 + (j * 4 + w) * 512);
            load_lds16(W + rb,      Bs0 + (j * 4 + w) * 512);
            load_lds16(W + rb + 32, Bs1 + (j * 4 + w) * 512);
        }
        __syncthreads();
        short8 af[4], bfr[4];
        #pragma unroll
        for (int mi = 0; mi < 4; ++mi)
            af[mi] = *(const short8*)&As0[(wm * 64 + mi * 16 + lq) * 32 + lg * 8];
        #pragma unroll
        for (int ni = 0; ni < 4; ++ni)
            bfr[ni] = *(const short8*)&Bs0[(wn * 64 + ni * 16 + lq) * 32 + lg * 8];
        #pragma unroll
        for (int mi = 0; mi < 4; ++mi)
            #pragma unroll
            for (int ni = 0; ni < 4; ++ni)
                acc[mi][ni] = __builtin_amdgcn_mfma_f32_16x16x32_bf16(
                    af[mi], bfr[ni], acc[mi][ni], 0, 0, 0);
        #pragma unroll
        for (int mi = 0; mi < 4; ++mi)
            af[mi] = *(const short8*)&As1[(wm * 64 + mi * 16 + lq) * 32 + lg * 8];
        #pragma unroll
        for (int ni = 0; ni < 4; ++ni)
            bfr[ni] = *(const short8*)&Bs1[(wn * 64 + ni * 16 + lq) * 32 + lg * 8];
        #pragma unroll
        for (int mi = 0; mi < 4; ++mi)
            #pragma unroll
            for (int ni = 0; ni < 4; ++ni)
                acc[mi][ni] = __builtin_amdgcn_mfma_f32_16x16x32_bf16(
                    af[mi], bfr[ni], acc[mi][ni], 0, 0, 0);
    }

    // ---------------- epilogue: bf16 scatter via LDS transpose ----------------
    __syncthreads();
    const int part = n0 >> 10;
    const int hh = ((n0 + wn * 64) & 1023) >> 6;
    const int mrow0 = m0 + wm * 64;
    const int bh = (mrow0 >> 11) * 16 + hh;
    const int tok0 = mrow0 & 2047;
    const float scl = (part == 0) ? 0.125f * 1.44269504089f : 1.0f;

    float bias4[4];
    #pragma unroll
    for (int ni = 0; ni < 4; ++ni)
        bias4[ni] = bias[n0 + wn * 64 + ni * 16 + lq];

    uint16_t* T = smem + w * 4608;                   // [64][72] bf16, wave-private
    if (part < 2) {
        #pragma unroll
        for (int mi = 0; mi < 4; ++mi)
            #pragma unroll
            for (int ni = 0; ni < 4; ++ni)
                #pragma unroll
                for (int r = 0; r < 4; ++r)
                    T[(mi * 16 + lg * 4 + r) * 72 + ni * 16 + lq] =
                        f2bf((acc[mi][ni][r] + bias4[ni]) * scl);
    } else {
        #pragma unroll
        for (int mi = 0; mi < 4; ++mi)
            #pragma unroll
            for (int ni = 0; ni < 4; ++ni)
                #pragma unroll
                for (int r = 0; r < 4; ++r)
                    T[(ni * 16 + lq) * 72 + mi * 16 + lg * 4 + r] =
                        f2bf(acc[mi][ni][r] + bias4[ni]);
    }

    const int a0 = l >> 3, b8 = (l & 7) * 8;
    #pragma unroll
    for (int i = 0; i < 8; ++i) {
        int a = i * 8 + a0;
        short8 u = *(short8*)&T[a * 72 + b8];
        uint16_t* p;
        if (part < 2) {
            uint16_t* dst = (part == 0) ? Qb : Kb;
            p = dst + ((size_t)bh * 2048 + tok0 + a) * 64 + b8;
        } else {
            p = Vt + ((size_t)bh * 64 + a) * 2048 + tok0 + b8;
        }
        *(short8*)p = u;
    }
}

// ======================= MFMA flash attention (paired, 4-way kv-split) ==========
// 512 blocks x 256 thr = 2048 waves, ALL co-resident (2 blocks/CU at VGPR~176;
// r20's regression was residency: 1024 blocks ran in 2 batches). Block handles
// q-block pair {x, 31-x} sequentially -> uniform ~9 wave-steps/block (vs r19's
// 16-step straggler). Wave w owns kv tiles kt === w (mod 4). Guarded tree merge
// per half (r20-verified correct). LDS 54.3KB x 2 blocks = 108.6KB < 160.
__device__ __forceinline__ void loadK8(const uint16_t* kp, short8 (&d)[8]) {
    #pragma unroll
    for (int n = 0; n < 4; ++n) {
        d[2 * n]     = *(const short8*)(kp + n * 1024);
        d[2 * n + 1] = *(const short8*)(kp + n * 1024 + 32);
    }
}
__device__ __forceinline__ void loadV8(const uint16_t* vp, short8 (&d)[8]) {
    #pragma unroll
    for (int n = 0; n < 4; ++n) {
        d[2 * n]     = *(const short8*)(vp + n * 32768);
        d[2 * n + 1] = *(const short8*)(vp + n * 32768 + 32);
    }
}

#define DEFER_THR 11.5f   // ~8 nats in log2 units

__global__ __launch_bounds__(256) void attn_mfma(
    const uint16_t* __restrict__ Q, const uint16_t* __restrict__ K,
    const uint16_t* __restrict__ Vt, uint16_t* __restrict__ Y)
{
    const int id = blockIdx.x;
    const int bh = id & 31;               // id%8 -> stable XCD per bh group
    const int xp = id >> 5;               // 0..15 pair index

    const int wv = threadIdx.x >> 6;      // kv residue class this wave owns (0..3)
    const int lane = threadIdx.x & 63;
    const int lq = lane & 15;
    const int lg = lane >> 4;

    __shared__ __align__(16) uint16_t Pl[4][2][16][72];  // [wave][pair-slot]
    __shared__ float  Yreg[2][64][68];                   // merge y regions (padded)
    __shared__ float2 MLreg[2][64];                      // merge (m, l) regions

    const uint16_t* Kb = K + (size_t)bh * (2048 * 64);
    const uint16_t* Vb = Vt + (size_t)bh * (64 * 2048);
    const int b = bh >> 4, h = bh & 15;

    for (int half = 0; half < 2; ++half) {
        const int blk = half ? (31 - xp) : xp;
        const int qt = blk;               // last kv tile index
        const int q0 = blk * 64;

        short8 qf[4][2];
        #pragma unroll
        for (int sub = 0; sub < 4; ++sub) {
            const uint16_t* qb = Q + ((size_t)bh * 2048 + q0 + sub * 16 + lq) * 64 + lg * 8;
            qf[sub][0] = *(const short8*)qb;
            qf[sub][1] = *(const short8*)(qb + 32);
        }

        f32x4 y[4][4] = {};
        float m[4]    = {-INFINITY, -INFINITY, -INFINITY, -INFINITY};
        float lsum[4] = {0.f, 0.f, 0.f, 0.f};

        const uint16_t* kp = Kb + ((size_t)(wv * 64 + lq)) * 64 + lg * 8;
        const uint16_t* vp = Vb + (size_t)lq * 2048 + wv * 64 + lg * 8;

        short8 kf[8], vv[8];

        auto qkpair = [&](f32x4 (&z)[2][4], int s0) {
            __builtin_amdgcn_s_setprio(1);
            #pragma unroll
            for (int p = 0; p < 2; ++p)
                #pragma unroll
                for (int n = 0; n < 4; ++n) {
                    f32x4 t = {};
                    t = __builtin_amdgcn_mfma_f32_16x16x32_bf16(kf[2 * n], qf[s0 + p][0], t, 0, 0, 0);
                    z[p][n] = __builtin_amdgcn_mfma_f32_16x16x32_bf16(kf[2 * n + 1], qf[s0 + p][1], t, 0, 0, 0);
                }
            __builtin_amdgcn_s_setprio(0);
        };

        auto smpv = [&](f32x4 (&z)[2][4], int s0, int kv0, bool domask) {
            if (domask) {
                #pragma unroll
                for (int p = 0; p < 2; ++p) {
                    const int qrow = q0 + (s0 + p) * 16 + lq;
                    #pragma unroll
                    for (int n = 0; n < 4; ++n) {
                        const int kvb = kv0 + n * 16 + lg * 4;
                        #pragma unroll
                        for (int r = 0; r < 4; ++r)
                            if (kvb + r > qrow) z[p][n][r] = -INFINITY;
                    }
                }
            }
            float mt[2];
            #pragma unroll
            for (int p = 0; p < 2; ++p) {
                float t = -INFINITY;
                #pragma unroll
                for (int n = 0; n < 4; ++n)
                    #pragma unroll
                    for (int r = 0; r < 4; ++r)
                        t = fmaxf(t, z[p][n][r]);
                mt[p] = t;
            }
            const float g = fmaxf(mt[0] - m[s0], mt[1] - m[s0 + 1]);
            const bool skip = __all(g <= DEFER_THR);
            if (!skip) {
                #pragma unroll
                for (int p = 0; p < 2; ++p) {
                    const int s = s0 + p;
                    float mf = fmaxf(mt[p], __shfl_xor(mt[p], 16));
                    mf = fmaxf(mf, __shfl_xor(mf, 32));
                    const float mn = fmaxf(m[s], mf);
                    const float sc = exp2f(m[s] - mn);
                    m[s] = mn;
                    lsum[s] *= sc;
                    float scy[4];
                    #pragma unroll
                    for (int r = 0; r < 4; ++r) scy[r] = __shfl(sc, lg * 4 + r);
                    #pragma unroll
                    for (int n = 0; n < 4; ++n)
                        #pragma unroll
                        for (int r = 0; r < 4; ++r)
                            y[s][n][r] *= scy[r];
                }
            }
            float ps[2] = {0.f, 0.f};
            #pragma unroll
            for (int p = 0; p < 2; ++p) {
                const int s = s0 + p;
                #pragma unroll
                for (int n = 0; n < 4; ++n) {
                    float e0 = exp2f(z[p][n][0] - m[s]);
                    float e1 = exp2f(z[p][n][1] - m[s]);
                    float e2 = exp2f(z[p][n][2] - m[s]);
                    float e3 = exp2f(z[p][n][3] - m[s]);
                    ps[p] += (e0 + e1) + (e2 + e3);
                    uint32_t p0, p1;
                    asm("v_cvt_pk_bf16_f32 %0, %1, %2" : "=v"(p0) : "v"(e0), "v"(e1));
                    asm("v_cvt_pk_bf16_f32 %0, %1, %2" : "=v"(p1) : "v"(e2), "v"(e3));
                    uint2 u; u.x = p0; u.y = p1;
                    *(uint2*)&Pl[wv][p][lq][n * 16 + lg * 4] = u;
                }
            }
            lsum[s0] += ps[0];
            lsum[s0 + 1] += ps[1];

            short8 pa[2][2];
            #pragma unroll
            for (int p = 0; p < 2; ++p) {
                pa[p][0] = *(short8*)&Pl[wv][p][lq][lg * 8];
                pa[p][1] = *(short8*)&Pl[wv][p][lq][lg * 8 + 32];
            }
            __builtin_amdgcn_s_setprio(1);
            #pragma unroll
            for (int p = 0; p < 2; ++p) {
                const int s = s0 + p;
                #pragma unroll
                for (int n = 0; n < 4; ++n) {
                    y[s][n] = __builtin_amdgcn_mfma_f32_16x16x32_bf16(pa[p][0], vv[2 * n], y[s][n], 0, 0, 0);
                    y[s][n] = __builtin_amdgcn_mfma_f32_16x16x32_bf16(pa[p][1], vv[2 * n + 1], y[s][n], 0, 0, 0);
                }
            }
            __builtin_amdgcn_s_setprio(0);
        };

        if (wv <= qt) {
            loadK8(kp, kf);
            int kt = wv;
            while (true) {
                const bool last = (kt + 4 > qt);
                const bool domask = (kt == qt);
                const int kv0 = kt * 64;
                loadV8(vp, vv);
                f32x4 z[2][4];
                qkpair(z, 0);
                smpv(z, 0, kv0, domask);
                qkpair(z, 2);
                if (!last) loadK8(kp + 16384, kf);
                smpv(z, 2, kv0, domask);
                if (last) break;
                kp += 16384; vp += 256; kt += 4;
            }
        }

        // ---- reduce per-lane lsum across lg groups ----
        float ls[4];
        #pragma unroll
        for (int s = 0; s < 4; ++s) {
            float t = lsum[s];
            t += __shfl_xor(t, 16);
            t += __shfl_xor(t, 32);
            ls[s] = t;
        }

        auto mergeFrom = [&](int reg) {
            #pragma unroll
            for (int s = 0; s < 4; ++s) {
                float2 o = MLreg[reg][s * 16 + lq];
                const float mo = o.x, lo = o.y;
                const float mx = fmaxf(m[s], mo);
                const float w0 = (ls[s] == 0.f) ? 0.f : exp2f(m[s] - mx);
                const float w1 = (lo == 0.f) ? 0.f : exp2f(mo - mx);
                const float ln = ls[s] * w0 + lo * w1;
                float w0r[4], w1r[4];
                #pragma unroll
                for (int r = 0; r < 4; ++r) {
                    w0r[r] = __shfl(w0, lg * 4 + r);
                    w1r[r] = __shfl(w1, lg * 4 + r);
                }
                #pragma unroll
                for (int n = 0; n < 4; ++n)
                    #pragma unroll
                    for (int r = 0; r < 4; ++r)
                        y[s][n][r] = y[s][n][r] * w0r[r] +
                                     Yreg[reg][s * 16 + lg * 4 + r][n * 16 + lq] * w1r[r];
                m[s] = mx;
                ls[s] = ln;
            }
        };
        auto postTo = [&](int reg) {
            #pragma unroll
            for (int s = 0; s < 4; ++s) {
                #pragma unroll
                for (int n = 0; n < 4; ++n)
                    #pragma unroll
                    for (int r = 0; r < 4; ++r)
                        Yreg[reg][s * 16 + lg * 4 + r][n * 16 + lq] = y[s][n][r];
                if (lg == 0) MLreg[reg][s * 16 + lq] = make_float2(m[s], ls[s]);
            }
        };

        // stage A: waves 1,3 post; waves 0,2 merge
        if (wv == 1) postTo(0);
        if (wv == 3) postTo(1);
        __syncthreads();
        if (wv == 0) mergeFrom(0);
        if (wv == 2) mergeFrom(1);
        __syncthreads();
        // stage B: wave 2 posts merged; wave 0 finalizes
        if (wv == 2) postTo(0);
        __syncthreads();
        if (wv == 0) {
            mergeFrom(0);
            #pragma unroll
            for (int s = 0; s < 4; ++s) {
                const float inv = 1.0f / ls[s];
                float invy[4];
                #pragma unroll
                for (int r = 0; r < 4; ++r) invy[r] = __shfl(inv, lg * 4 + r);
                #pragma unroll
                for (int r = 0; r < 4; ++r) {
                    int token = b * 2048 + q0 + s * 16 + lg * 4 + r;
                    uint16_t* yrow = Y + (size_t)token * 1024 + h * 64;
                    #pragma unroll
                    for (int n = 0; n < 4; ++n)
                        yrow[n * 16 + lq] = f2bf(y[s][n][r] * invy[r]);
                }
            }
        }
        __syncthreads();   // Yreg/MLreg/Pl reused next half
    }
}

// ======================= output projection (MFMA, fp32 out) =======================
// out[4096,1024] = Y(bf16) @ Wo(bf16)^T + bo. BK=64 + XCD column affinity.
__global__ __launch_bounds__(256) void gemm_proj(
    const uint16_t* __restrict__ Yin, const uint16_t* __restrict__ W,
    const float* __restrict__ bias, float* __restrict__ out)
{
    __shared__ __align__(16) uint16_t smem[16384];   // 4 x [128][32] = 32 KB
    uint16_t* As0 = smem;
    uint16_t* As1 = smem + 4096;
    uint16_t* Bs0 = smem + 8192;
    uint16_t* Bs1 = smem + 12288;

    const int tid = threadIdx.x;
    const int w = tid >> 6, l = tid & 63;
    const int lq = l & 15, lg = l >> 4;
    const int wm = w >> 1, wn = w & 1;

    const int flat = blockIdx.x + blockIdx.y * 8;
    const int n0 = (flat & 7) * 128;
    const int m0 = (flat >> 3) * 128;

    f32x4 acc[4][4] = {};

    for (int k0 = 0; k0 < 1024; k0 += 64) {
        __syncthreads();
        #pragma unroll
        for (int j = 0; j < 2; ++j) {
            const int c = (j * 4 + w) * 64 + l;
            const size_t ra = (size_t)(m0 + (c >> 2)) * 1024 + k0 + (c & 3) * 8;
            const size_t rb = (size_t)(n0 + (c >> 2)) * 1024 + k0 + (c & 3) * 8;
            load_lds16(Yin + ra,      As0 + (j * 4 + w) * 512);
            load_lds16(Yin + ra + 32, As1 + (j * 4 + w) * 512);
            load_lds16(W + rb,        Bs0 + (j * 4 + w) * 512);
            load_lds16(W + rb + 32,   Bs1 + (j * 4 + w) * 512);
        }
        __syncthreads();
        short8 af[4], bfr[4];
        #pragma unroll
        for (int mi = 0; mi < 4; ++mi)
            af[mi] = *(const short8*)&As0[(wm * 64 + mi * 16 + lq) * 32 + lg * 8];
        #pragma unroll
        for (int ni = 0; ni < 4; ++ni)
            bfr[ni] = *(const short8*)&Bs0[(wn * 64 + ni * 16 + lq) * 32 + lg * 8];
        #pragma unroll
        for (int mi = 0; mi < 4; ++mi)
            #pragma unroll
            for (int ni = 0; ni < 4; ++ni)
                acc[mi][ni] = __builtin_amdgcn_mfma_f32_16x16x32_bf16(
                    af[mi], bfr[ni], acc[mi][ni], 0, 0, 0);
        #pragma unroll
        for (int mi = 0; mi < 4; ++mi)
            af[mi] = *(const short8*)&As1[(wm * 64 + mi * 16 + lq) * 32 + lg * 8];
        #pragma unroll
        for (int ni = 0; ni < 4; ++ni)
            bfr[ni] = *(const short8*)&Bs1[(wn * 64 + ni * 16 + lq) * 32 + lg * 8];
        #pragma unroll
        for (int mi = 0; mi < 4; ++mi)
            #pragma unroll
            for (int ni = 0; ni < 4; ++ni)
                acc[mi][ni] = __builtin_amdgcn_mfma_f32_16x16x32_bf16(
                    af[mi], bfr[ni], acc[mi][ni], 0, 0, 0);
    }

    const int mrow0 = m0 + wm * 64;
    const int ncol0 = n0 + wn * 64;
    float bias4[4];
    #pragma unroll
    for (int ni = 0; ni < 4; ++ni)
        bias4[ni] = bias[ncol0 + ni * 16 + lq];

    #pragma unroll
    for (int mi = 0; mi < 4; ++mi)
        #pragma unroll
        for (int r = 0; r < 4; ++r) {
            const size_t rowoff = (size_t)(mrow0 + mi * 16 + lg * 4 + r) * 1024;
            #pragma unroll
            for (int ni = 0; ni < 4; ++ni)
                out[rowoff + ncol0 + ni * 16 + lq] = acc[mi][ni][r] + bias4[ni];
        }
}

// ======================= launcher =======================

extern "C" void kernel_launch(void* const* d_in, const int* in_sizes, int n_in,
                              void* d_out, int out_size, void* d_ws, size_t ws_size,
                              hipStream_t stream) {
    const float* x    = (const float*)d_in[0];
    // d_in[1] (causal mask) applied structurally.
    const float* Wqkv = (const float*)d_in[2];
    const float* bqkv = (const float*)d_in[3];
    const float* Wo   = (const float*)d_in[4];
    const float* bo   = (const float*)d_in[5];

    const size_t QK = (size_t)BB * HH * NN * SS;  // 4,194,304

    uint16_t* Xb  = (uint16_t*)d_ws;
    uint16_t* Wqb = Xb + XE;
    uint16_t* Wob = Wqb + WQE;
    uint16_t* Qb  = Wob + WOE;
    uint16_t* Kb  = Qb + QK;
    uint16_t* Vt  = Kb + QK;
    uint16_t* Yb  = Vt + QK;

    cvt_all<<<(XE + WQE + WOE) / 8 / 256, 256, 0, stream>>>(x, Wqkv, Wo, Xb);
    gemm_qkv<<<dim3(24, 32), 256, 0, stream>>>(Xb, Wqb, bqkv, Qb, Kb, Vt);
    attn_mfma<<<512, 256, 0, stream>>>(Qb, Kb, Vt, Yb);
    gemm_proj<<<dim3(8, 32), 256, 0, stream>>>(Yb, Wob, bo, (float*)d_out);
}

// Round 22
// 134.401 us; speedup vs baseline: 1.0699x; 1.0612x over previous
//
#include <hip/hip_runtime.h>
#include <hip/hip_bf16.h>
#include <stdint.h>

// Problem constants: B=2, N=2048, D=1024, H=16, head dim s=64.
// Global I/O fp32; internal X/W/Q/K/V/Y intermediates bf16 in d_ws.
// Q is pre-scaled by 0.125*log2e so attention softmax runs in exp2 domain.
#define BB 2
#define NN 2048
#define DD 1024
#define HH 16
#define SS 64

typedef short short8 __attribute__((ext_vector_type(8)));
typedef float f32x4 __attribute__((ext_vector_type(4)));

__device__ __forceinline__ float bf2f(uint16_t u) {
    return __uint_as_float(((uint32_t)u) << 16);
}
__device__ __forceinline__ uint16_t f2bf(float f) {
    uint32_t u = __float_as_uint(f);
    return (uint16_t)((u + 0x7FFFu + ((u >> 16) & 1u)) >> 16);  // RNE
}
__device__ __forceinline__ short8 cvt8(float4 a, float4 b) {
    short8 s;
    s[0] = (short)f2bf(a.x); s[1] = (short)f2bf(a.y);
    s[2] = (short)f2bf(a.z); s[3] = (short)f2bf(a.w);
    s[4] = (short)f2bf(b.x); s[5] = (short)f2bf(b.y);
    s[6] = (short)f2bf(b.z); s[7] = (short)f2bf(b.w);
    return s;
}

__device__ __forceinline__ void load_lds16(const uint16_t* g, uint16_t* l) {
    __builtin_amdgcn_global_load_lds(
        (const __attribute__((address_space(1))) void*)g,
        (__attribute__((address_space(3))) void*)l, 16, 0, 0);
}

#define XE  (4096 * 1024)
#define WQE (3072 * 1024)
#define WOE (1024 * 1024)

// ======================= fused fp32 -> bf16 bulk convert =======================
__global__ __launch_bounds__(256) void cvt_all(
    const float* __restrict__ x, const float* __restrict__ wq,
    const float* __restrict__ wo, uint16_t* __restrict__ dst)
{
    int i = (blockIdx.x * 256 + threadIdx.x) * 8;
    const float* src;
    int off;
    if (i < XE)            { src = x;  off = i; }
    else if (i < XE + WQE) { src = wq; off = i - XE; }
    else                   { src = wo; off = i - XE - WQE; }
    float4 a = *(const float4*)(src + off);
    float4 b = *(const float4*)(src + off + 4);
    *(short8*)(dst + i) = cvt8(a, b);
}

// ======================= QKV projection (MFMA, bf16 in) =======================
// C[4096,3072] = X[4096,1024] @ Wqkv[3072,1024]^T + bqkv
// -> Q bf16 (x0.125*log2e) [bh][2048][64], K bf16 [bh][2048][64], V^T [bh][64][2048]
// BK=64 + XCD swizzle (unchanged from round 15).
__global__ __launch_bounds__(256) void gemm_qkv(
    const uint16_t* __restrict__ X, const uint16_t* __restrict__ W,
    const float* __restrict__ bias,
    uint16_t* __restrict__ Qb, uint16_t* __restrict__ Kb, uint16_t* __restrict__ Vt)
{
    __shared__ __align__(16) uint16_t smem[18432];   // 36,864 B
    uint16_t* As0 = smem;            // [128][32]
    uint16_t* As1 = smem + 4096;
    uint16_t* Bs0 = smem + 8192;
    uint16_t* Bs1 = smem + 12288;

    const int tid = threadIdx.x;
    const int w = tid >> 6, l = tid & 63;
    const int lq = l & 15, lg = l >> 4;
    const int wm = w >> 1, wn = w & 1;

    const int flat = blockIdx.x + blockIdx.y * 24;
    const int xcd = flat & 7, g = flat >> 3;
    const int n0 = (xcd * 3 + (g % 3)) * 128;
    const int m0 = (g / 3) * 128;

    f32x4 acc[4][4] = {};

    for (int k0 = 0; k0 < 1024; k0 += 64) {
        __syncthreads();
        #pragma unroll
        for (int j = 0; j < 2; ++j) {
            const int c = (j * 4 + w) * 64 + l;
            const size_t ra = (size_t)(m0 + (c >> 2)) * 1024 + k0 + (c & 3) * 8;
            const size_t rb = (size_t)(n0 + (c >> 2)) * 1024 + k0 + (c & 3) * 8;
            load_lds16(X + ra,      As0 + (j * 4 + w) * 512);
            load_lds16(X + ra + 32, As1 + (j * 4 + w) * 512);
            load_lds16(W + rb,      Bs0 + (j * 4 + w) * 512);
            load_lds16(W + rb + 32, Bs1 + (j * 4 + w) * 512);
        }
        __syncthreads();
        short8 af[4], bfr[4];
        #pragma unroll
        for (int mi = 0; mi < 4; ++mi)
            af[mi] = *(const short8*)&As0[(wm * 64 + mi * 16 + lq) * 32 + lg * 8];
        #pragma unroll
        for (int ni = 0; ni < 4; ++ni)
            bfr[ni] = *(const short8*)&Bs0[(wn * 64 + ni * 16 + lq) * 32 + lg * 8];
        #pragma unroll
        for (int mi = 0; mi < 4; ++mi)
            #pragma unroll
            for (int ni = 0; ni < 4; ++ni)
                acc[mi][ni] = __builtin_amdgcn_mfma_f32_16x16x32_bf16(
                    af[mi], bfr[ni], acc[mi][ni], 0, 0, 0);
        #pragma unroll
        for (int mi = 0; mi < 4; ++mi)
            af[mi] = *(const short8*)&As1[(wm * 64 + mi * 16 + lq) * 32 + lg * 8];
        #pragma unroll
        for (int ni = 0; ni < 4; ++ni)
            bfr[ni] = *(const short8*)&Bs1[(wn * 64 + ni * 16 + lq) * 32 + lg * 8];
        #pragma unroll
        for (int mi = 0; mi < 4; ++mi)
            #pragma unroll
            for (int ni = 0; ni < 4; ++ni)
                acc[mi][ni] = __builtin_amdgcn_mfma_f32_16x16x32_bf16(
                    af[mi], bfr[ni], acc[mi][ni], 0, 0, 0);
    }

    // ---------------- epilogue: bf16 scatter via LDS transpose ----------------
    __syncthreads();
    const int part = n0 >> 10;
    const int hh = ((n0 + wn * 64) & 1023) >> 6;
    const int mrow0 = m0 + wm * 64;
    const int bh = (mrow0 >> 11) * 16 + hh;
    const int tok0 = mrow0 & 2047;
    const float scl = (part == 0) ? 0.125f * 1.44269504089f : 1.0f;

    float bias4[4];
    #pragma unroll
    for (int ni = 0; ni < 4; ++ni)
        bias4[ni] = bias[n0 + wn * 64 + ni * 16 + lq];

    uint16_t* T = smem + w * 4608;                   // [64][72] bf16, wave-private
    if (part < 2) {
        #pragma unroll
        for (int mi = 0; mi < 4; ++mi)
            #pragma unroll
            for (int ni = 0; ni < 4; ++ni)
                #pragma unroll
                for (int r = 0; r < 4; ++r)
                    T[(mi * 16 + lg * 4 + r) * 72 + ni * 16 + lq] =
                        f2bf((acc[mi][ni][r] + bias4[ni]) * scl);
    } else {
        #pragma unroll
        for (int mi = 0; mi < 4; ++mi)
            #pragma unroll
            for (int ni = 0; ni < 4; ++ni)
                #pragma unroll
                for (int r = 0; r < 4; ++r)
                    T[(ni * 16 + lq) * 72 + mi * 16 + lg * 4 + r] =
                        f2bf(acc[mi][ni][r] + bias4[ni]);
    }

    const int a0 = l >> 3, b8 = (l & 7) * 8;
    #pragma unroll
    for (int i = 0; i < 8; ++i) {
        int a = i * 8 + a0;
        short8 u = *(short8*)&T[a * 72 + b8];
        uint16_t* p;
        if (part < 2) {
            uint16_t* dst = (part == 0) ? Qb : Kb;
            p = dst + ((size_t)bh * 2048 + tok0 + a) * 64 + b8;
        } else {
            p = Vt + ((size_t)bh * 64 + a) * 2048 + tok0 + b8;
        }
        *(short8*)p = u;
    }
}

// ======================= MFMA flash attention (64 q-rows/wave, kv-split) ========
// r19 structure (best verified: attn 57.4us) + CU-level load balancing:
// the old blk = 31-(id>>5) put 32 consecutive ids (one CU-refill round) on the
// SAME blk, so each CU's 4 resident blocks had identical step counts (straggler
// CUs ran 16 steps while light CUs idled after 1 — Occupancy 9.8%). New
// bijective remap gives every CU blocks {r, 31-r, r+8, 23-r}: per-CU step-sum
// constant (34). bh = id&31 untouched -> XCD K/V affinity preserved.
__device__ __forceinline__ void loadK8(const uint16_t* kp, short8 (&d)[8]) {
    #pragma unroll
    for (int n = 0; n < 4; ++n) {
        d[2 * n]     = *(const short8*)(kp + n * 1024);
        d[2 * n + 1] = *(const short8*)(kp + n * 1024 + 32);
    }
}
__device__ __forceinline__ void loadV8(const uint16_t* vp, short8 (&d)[8]) {
    #pragma unroll
    for (int n = 0; n < 4; ++n) {
        d[2 * n]     = *(const short8*)(vp + n * 32768);
        d[2 * n + 1] = *(const short8*)(vp + n * 32768 + 32);
    }
}

#define DEFER_THR 11.5f   // ~8 nats in log2 units

__global__ __launch_bounds__(128) void attn_mfma(
    const uint16_t* __restrict__ Q, const uint16_t* __restrict__ K,
    const uint16_t* __restrict__ Vt, uint16_t* __restrict__ Y)
{
    const int id = blockIdx.x;
    const int bh = id & 31;               // id%8 -> stable XCD per bh group
    const int g = id >> 5;                // 0..31
    const int hi = (g >> 3) & 1;
    const int rest = ((g >> 4) << 3) | (g & 7);   // 0..15
    const int blk = hi ? (31 - rest) : rest;      // balanced bijective remap
    const int qt = blk;                   // last kv tile index
    const int q0 = blk * 64;

    const int wv = threadIdx.x >> 6;      // kv-parity this wave owns
    const int lane = threadIdx.x & 63;
    const int lq = lane & 15;
    const int lg = lane >> 4;

    __shared__ __align__(16) uint16_t Pl[2][2][16][72];  // [wave][pair-slot]
    __shared__ float  My[64][68];                        // wave1 partial y (padded)
    __shared__ float2 Mml[64];                           // wave1 (m, lsum) per q-row

    const uint16_t* Kb = K + (size_t)bh * (2048 * 64);
    const uint16_t* Vb = Vt + (size_t)bh * (64 * 2048);
    const int b = bh >> 4, h = bh & 15;

    short8 qf[4][2];
    #pragma unroll
    for (int sub = 0; sub < 4; ++sub) {
        const uint16_t* qb = Q + ((size_t)bh * 2048 + q0 + sub * 16 + lq) * 64 + lg * 8;
        qf[sub][0] = *(const short8*)qb;
        qf[sub][1] = *(const short8*)(qb + 32);
    }

    f32x4 y[4][4] = {};
    float m[4]    = {-INFINITY, -INFINITY, -INFINITY, -INFINITY};
    float lsum[4] = {0.f, 0.f, 0.f, 0.f};

    const uint16_t* kp = Kb + ((size_t)(wv * 64 + lq)) * 64 + lg * 8;
    const uint16_t* vp = Vb + (size_t)lq * 2048 + wv * 64 + lg * 8;

    short8 kf[8], vv[8];

    // swapped QK^T for a sub-pair: z[p][n][r] = S[q0+(s0+p)*16+lq][kv0+n*16+lg*4+r]
    auto qkpair = [&](f32x4 (&z)[2][4], int s0) {
        __builtin_amdgcn_s_setprio(1);
        #pragma unroll
        for (int p = 0; p < 2; ++p)
            #pragma unroll
            for (int n = 0; n < 4; ++n) {
                f32x4 t = {};
                t = __builtin_amdgcn_mfma_f32_16x16x32_bf16(kf[2 * n], qf[s0 + p][0], t, 0, 0, 0);
                z[p][n] = __builtin_amdgcn_mfma_f32_16x16x32_bf16(kf[2 * n + 1], qf[s0 + p][1], t, 0, 0, 0);
            }
        __builtin_amdgcn_s_setprio(0);
    };

    auto smpv = [&](f32x4 (&z)[2][4], int s0, int kv0, bool domask) {
        if (domask) {
            #pragma unroll
            for (int p = 0; p < 2; ++p) {
                const int qrow = q0 + (s0 + p) * 16 + lq;
                #pragma unroll
                for (int n = 0; n < 4; ++n) {
                    const int kvb = kv0 + n * 16 + lg * 4;
                    #pragma unroll
                    for (int r = 0; r < 4; ++r)
                        if (kvb + r > qrow) z[p][n][r] = -INFINITY;
                }
            }
        }
        float mt[2];
        #pragma unroll
        for (int p = 0; p < 2; ++p) {
            float t = -INFINITY;
            #pragma unroll
            for (int n = 0; n < 4; ++n)
                #pragma unroll
                for (int r = 0; r < 4; ++r)
                    t = fmaxf(t, z[p][n][r]);
            mt[p] = t;
        }
        const float gd = fmaxf(mt[0] - m[s0], mt[1] - m[s0 + 1]);
        const bool skip = __all(gd <= DEFER_THR);
        if (!skip) {
            #pragma unroll
            for (int p = 0; p < 2; ++p) {
                const int s = s0 + p;
                float mf = fmaxf(mt[p], __shfl_xor(mt[p], 16));
                mf = fmaxf(mf, __shfl_xor(mf, 32));
                const float mn = fmaxf(m[s], mf);
                const float sc = exp2f(m[s] - mn);
                m[s] = mn;
                lsum[s] *= sc;
                float scy[4];
                #pragma unroll
                for (int r = 0; r < 4; ++r) scy[r] = __shfl(sc, lg * 4 + r);
                #pragma unroll
                for (int n = 0; n < 4; ++n)
                    #pragma unroll
                    for (int r = 0; r < 4; ++r)
                        y[s][n][r] *= scy[r];
            }
        }
        float ps[2] = {0.f, 0.f};
        #pragma unroll
        for (int p = 0; p < 2; ++p) {
            const int s = s0 + p;
            #pragma unroll
            for (int n = 0; n < 4; ++n) {
                float e0 = exp2f(z[p][n][0] - m[s]);
                float e1 = exp2f(z[p][n][1] - m[s]);
                float e2 = exp2f(z[p][n][2] - m[s]);
                float e3 = exp2f(z[p][n][3] - m[s]);
                ps[p] += (e0 + e1) + (e2 + e3);
                uint32_t p0, p1;
                asm("v_cvt_pk_bf16_f32 %0, %1, %2" : "=v"(p0) : "v"(e0), "v"(e1));
                asm("v_cvt_pk_bf16_f32 %0, %1, %2" : "=v"(p1) : "v"(e2), "v"(e3));
                uint2 u; u.x = p0; u.y = p1;
                *(uint2*)&Pl[wv][p][lq][n * 16 + lg * 4] = u;
            }
        }
        lsum[s0] += ps[0];
        lsum[s0 + 1] += ps[1];

        short8 pa[2][2];
        #pragma unroll
        for (int p = 0; p < 2; ++p) {
            pa[p][0] = *(short8*)&Pl[wv][p][lq][lg * 8];
            pa[p][1] = *(short8*)&Pl[wv][p][lq][lg * 8 + 32];
        }
        __builtin_amdgcn_s_setprio(1);
        #pragma unroll
        for (int p = 0; p < 2; ++p) {
            const int s = s0 + p;
            #pragma unroll
            for (int n = 0; n < 4; ++n) {
                y[s][n] = __builtin_amdgcn_mfma_f32_16x16x32_bf16(pa[p][0], vv[2 * n], y[s][n], 0, 0, 0);
                y[s][n] = __builtin_amdgcn_mfma_f32_16x16x32_bf16(pa[p][1], vv[2 * n + 1], y[s][n], 0, 0, 0);
            }
        }
        __builtin_amdgcn_s_setprio(0);
    };

    if (wv <= qt) {
        loadK8(kp, kf);
        int kt = wv;
        while (true) {
            const bool last = (kt + 2 > qt);
            const bool domask = (kt == qt);
            const int kv0 = kt * 64;
            loadV8(vp, vv);
            f32x4 z[2][4];
            qkpair(z, 0);
            smpv(z, 0, kv0, domask);
            qkpair(z, 2);
            if (!last) loadK8(kp + 8192, kf);   // consumed by both QK phases
            smpv(z, 2, kv0, domask);
            if (last) break;
            kp += 8192; vp += 128; kt += 2;
        }
    }

    // ---- reduce per-lane lsum across lg groups ----
    float ls[4];
    #pragma unroll
    for (int s = 0; s < 4; ++s) {
        float t = lsum[s];
        t += __shfl_xor(t, 16);
        t += __shfl_xor(t, 32);
        ls[s] = t;
    }

    // ---- merge: wave1 posts partials; wave0 combines + writes ----
    if (wv == 1) {
        #pragma unroll
        for (int s = 0; s < 4; ++s) {
            #pragma unroll
            for (int n = 0; n < 4; ++n)
                #pragma unroll
                for (int r = 0; r < 4; ++r)
                    My[s * 16 + lg * 4 + r][n * 16 + lq] = y[s][n][r];
            if (lg == 0) Mml[s * 16 + lq] = make_float2(m[s], ls[s]);
        }
    }
    __syncthreads();
    if (wv == 0) {
        #pragma unroll
        for (int s = 0; s < 4; ++s) {
            float2 o = Mml[s * 16 + lq];
            const float m1 = o.x, l1 = o.y;
            const float mx = fmaxf(m[s], m1);
            const float w0 = exp2f(m[s] - mx);
            const float w1 = exp2f(m1 - mx);
            const float inv = 1.0f / (ls[s] * w0 + l1 * w1);
            const float f0 = w0 * inv, f1 = w1 * inv;
            float f0r[4], f1r[4];
            #pragma unroll
            for (int r = 0; r < 4; ++r) {
                f0r[r] = __shfl(f0, lg * 4 + r);
                f1r[r] = __shfl(f1, lg * 4 + r);
            }
            #pragma unroll
            for (int r = 0; r < 4; ++r) {
                int token = b * 2048 + q0 + s * 16 + lg * 4 + r;
                uint16_t* yrow = Y + (size_t)token * 1024 + h * 64;
                #pragma unroll
                for (int n = 0; n < 4; ++n) {
                    float val = y[s][n][r] * f0r[r] +
                                My[s * 16 + lg * 4 + r][n * 16 + lq] * f1r[r];
                    yrow[n * 16 + lq] = f2bf(val);
                }
            }
        }
    }
}

// ======================= output projection (MFMA, fp32 out) =======================
// out[4096,1024] = Y(bf16) @ Wo(bf16)^T + bo. BK=64 + XCD column affinity.
__global__ __launch_bounds__(256) void gemm_proj(
    const uint16_t* __restrict__ Yin, const uint16_t* __restrict__ W,
    const float* __restrict__ bias, float* __restrict__ out)
{
    __shared__ __align__(16) uint16_t smem[16384];   // 4 x [128][32] = 32 KB
    uint16_t* As0 = smem;
    uint16_t* As1 = smem + 4096;
    uint16_t* Bs0 = smem + 8192;
    uint16_t* Bs1 = smem + 12288;

    const int tid = threadIdx.x;
    const int w = tid >> 6, l = tid & 63;
    const int lq = l & 15, lg = l >> 4;
    const int wm = w >> 1, wn = w & 1;

    const int flat = blockIdx.x + blockIdx.y * 8;
    const int n0 = (flat & 7) * 128;
    const int m0 = (flat >> 3) * 128;

    f32x4 acc[4][4] = {};

    for (int k0 = 0; k0 < 1024; k0 += 64) {
        __syncthreads();
        #pragma unroll
        for (int j = 0; j < 2; ++j) {
            const int c = (j * 4 + w) * 64 + l;
            const size_t ra = (size_t)(m0 + (c >> 2)) * 1024 + k0 + (c & 3) * 8;
            const size_t rb = (size_t)(n0 + (c >> 2)) * 1024 + k0 + (c & 3) * 8;
            load_lds16(Yin + ra,      As0 + (j * 4 + w) * 512);
            load_lds16(Yin + ra + 32, As1 + (j * 4 + w) * 512);
            load_lds16(W + rb,        Bs0 + (j * 4 + w) * 512);
            load_lds16(W + rb + 32,   Bs1 + (j * 4 + w) * 512);
        }
        __syncthreads();
        short8 af[4], bfr[4];
        #pragma unroll
        for (int mi = 0; mi < 4; ++mi)
            af[mi] = *(const short8*)&As0[(wm * 64 + mi * 16 + lq) * 32 + lg * 8];
        #pragma unroll
        for (int ni = 0; ni < 4; ++ni)
            bfr[ni] = *(const short8*)&Bs0[(wn * 64 + ni * 16 + lq) * 32 + lg * 8];
        #pragma unroll
        for (int mi = 0; mi < 4; ++mi)
            #pragma unroll
            for (int ni = 0; ni < 4; ++ni)
                acc[mi][ni] = __builtin_amdgcn_mfma_f32_16x16x32_bf16(
                    af[mi], bfr[ni], acc[mi][ni], 0, 0, 0);
        #pragma unroll
        for (int mi = 0; mi < 4; ++mi)
            af[mi] = *(const short8*)&As1[(wm * 64 + mi * 16 + lq) * 32 + lg * 8];
        #pragma unroll
        for (int ni = 0; ni < 4; ++ni)
            bfr[ni] = *(const short8*)&Bs1[(wn * 64 + ni * 16 + lq) * 32 + lg * 8];
        #pragma unroll
        for (int mi = 0; mi < 4; ++mi)
            #pragma unroll
            for (int ni = 0; ni < 4; ++ni)
                acc[mi][ni] = __builtin_amdgcn_mfma_f32_16x16x32_bf16(
                    af[mi], bfr[ni], acc[mi][ni], 0, 0, 0);
    }

    const int mrow0 = m0 + wm * 64;
    const int ncol0 = n0 + wn * 64;
    float bias4[4];
    #pragma unroll
    for (int ni = 0; ni < 4; ++ni)
        bias4[ni] = bias[ncol0 + ni * 16 + lq];

    #pragma unroll
    for (int mi = 0; mi < 4; ++mi)
        #pragma unroll
        for (int r = 0; r < 4; ++r) {
            const size_t rowoff = (size_t)(mrow0 + mi * 16 + lg * 4 + r) * 1024;
            #pragma unroll
            for (int ni = 0; ni < 4; ++ni)
                out[rowoff + ncol0 + ni * 16 + lq] = acc[mi][ni][r] + bias4[ni];
        }
}

// ======================= launcher =======================

extern "C" void kernel_launch(void* const* d_in, const int* in_sizes, int n_in,
                              void* d_out, int out_size, void* d_ws, size_t ws_size,
                              hipStream_t stream) {
    const float* x    = (const float*)d_in[0];
    // d_in[1] (causal mask) applied structurally.
    const float* Wqkv = (const float*)d_in[2];
    const float* bqkv = (const float*)d_in[3];
    const float* Wo   = (const float*)d_in[4];
    const float* bo   = (const float*)d_in[5];

    const size_t QK = (size_t)BB * HH * NN * SS;  // 4,194,304

    uint16_t* Xb  = (uint16_t*)d_ws;
    uint16_t* Wqb = Xb + XE;
    uint16_t* Wob = Wqb + WQE;
    uint16_t* Qb  = Wob + WOE;
    uint16_t* Kb  = Qb + QK;
    uint16_t* Vt  = Kb + QK;
    uint16_t* Yb  = Vt + QK;

    cvt_all<<<(XE + WQE + WOE) / 8 / 256, 256, 0, stream>>>(x, Wqkv, Wo, Xb);
    gemm_qkv<<<dim3(24, 32), 256, 0, stream>>>(Xb, Wqb, bqkv, Qb, Kb, Vt);
    attn_mfma<<<1024, 128, 0, stream>>>(Qb, Kb, Vt, Yb);
    gemm_proj<<<dim3(8, 32), 256, 0, stream>>>(Yb, Wob, bo, (float*)d_out);
}

// Round 23
// 123.788 us; speedup vs baseline: 1.1617x; 1.0857x over previous
//
#include <hip/hip_runtime.h>
#include <hip/hip_bf16.h>
#include <stdint.h>

// Problem constants: B=2, N=2048, D=1024, H=16, head dim s=64.
// Global I/O fp32; internal X/W/Q/K/V/Y intermediates bf16 in d_ws.
// Q is pre-scaled by 0.125*log2e so attention softmax runs in exp2 domain.
#define BB 2
#define NN 2048
#define DD 1024
#define HH 16
#define SS 64

typedef short short8 __attribute__((ext_vector_type(8)));
typedef float f32x4 __attribute__((ext_vector_type(4)));

__device__ __forceinline__ float bf2f(uint16_t u) {
    return __uint_as_float(((uint32_t)u) << 16);
}
__device__ __forceinline__ uint16_t f2bf(float f) {
    uint32_t u = __float_as_uint(f);
    return (uint16_t)((u + 0x7FFFu + ((u >> 16) & 1u)) >> 16);  // RNE
}
__device__ __forceinline__ short8 cvt8(float4 a, float4 b) {
    short8 s;
    s[0] = (short)f2bf(a.x); s[1] = (short)f2bf(a.y);
    s[2] = (short)f2bf(a.z); s[3] = (short)f2bf(a.w);
    s[4] = (short)f2bf(b.x); s[5] = (short)f2bf(b.y);
    s[6] = (short)f2bf(b.z); s[7] = (short)f2bf(b.w);
    return s;
}

__device__ __forceinline__ void load_lds16(const uint16_t* g, uint16_t* l) {
    __builtin_amdgcn_global_load_lds(
        (const __attribute__((address_space(1))) void*)g,
        (__attribute__((address_space(3))) void*)l, 16, 0, 0);
}

#define XE  (4096 * 1024)
#define WQE (3072 * 1024)
#define WOE (1024 * 1024)

// ======================= fused fp32 -> bf16 bulk convert =======================
__global__ __launch_bounds__(256) void cvt_all(
    const float* __restrict__ x, const float* __restrict__ wq,
    const float* __restrict__ wo, uint16_t* __restrict__ dst)
{
    int i = (blockIdx.x * 256 + threadIdx.x) * 8;
    const float* src;
    int off;
    if (i < XE)            { src = x;  off = i; }
    else if (i < XE + WQE) { src = wq; off = i - XE; }
    else                   { src = wo; off = i - XE - WQE; }
    float4 a = *(const float4*)(src + off);
    float4 b = *(const float4*)(src + off + 4);
    *(short8*)(dst + i) = cvt8(a, b);
}

// ======================= QKV projection (MFMA, bf16 in) =======================
// C[4096,3072] = X[4096,1024] @ Wqkv[3072,1024]^T + bqkv
// -> Q bf16 (x0.125*log2e) [bh][2048][64], K bf16 [bh][2048][64], V^T [bh][64][2048]
// BK=64 + XCD swizzle (round-15 verified).
__global__ __launch_bounds__(256) void gemm_qkv(
    const uint16_t* __restrict__ X, const uint16_t* __restrict__ W,
    const float* __restrict__ bias,
    uint16_t* __restrict__ Qb, uint16_t* __restrict__ Kb, uint16_t* __restrict__ Vt)
{
    __shared__ __align__(16) uint16_t smem[18432];   // 36,864 B
    uint16_t* As0 = smem;            // [128][32]
    uint16_t* As1 = smem + 4096;
    uint16_t* Bs0 = smem + 8192;
    uint16_t* Bs1 = smem + 12288;

    const int tid = threadIdx.x;
    const int w = tid >> 6, l = tid & 63;
    const int lq = l & 15, lg = l >> 4;
    const int wm = w >> 1, wn = w & 1;

    const int flat = blockIdx.x + blockIdx.y * 24;
    const int xcd = flat & 7, g = flat >> 3;
    const int n0 = (xcd * 3 + (g % 3)) * 128;
    const int m0 = (g / 3) * 128;

    f32x4 acc[4][4] = {};

    for (int k0 = 0; k0 < 1024; k0 += 64) {
        __syncthreads();
        #pragma unroll
        for (int j = 0; j < 2; ++j) {
            const int c = (j * 4 + w) * 64 + l;
            const size_t ra = (size_t)(m0 + (c >> 2)) * 1024 + k0 + (c & 3) * 8;
            const size_t rb = (size_t)(n0 + (c >> 2)) * 1024 + k0 + (c & 3) * 8;
            load_lds16(X + ra,      As0 + (j * 4 + w) * 512);
            load_lds16(X + ra + 32, As1 + (j * 4 + w) * 512);
            load_lds16(W + rb,      Bs0 + (j * 4 + w) * 512);
            load_lds16(W + rb + 32, Bs1 + (j * 4 + w) * 512);
        }
        __syncthreads();
        short8 af[4], bfr[4];
        #pragma unroll
        for (int mi = 0; mi < 4; ++mi)
            af[mi] = *(const short8*)&As0[(wm * 64 + mi * 16 + lq) * 32 + lg * 8];
        #pragma unroll
        for (int ni = 0; ni < 4; ++ni)
            bfr[ni] = *(const short8*)&Bs0[(wn * 64 + ni * 16 + lq) * 32 + lg * 8];
        #pragma unroll
        for (int mi = 0; mi < 4; ++mi)
            #pragma unroll
            for (int ni = 0; ni < 4; ++ni)
                acc[mi][ni] = __builtin_amdgcn_mfma_f32_16x16x32_bf16(
                    af[mi], bfr[ni], acc[mi][ni], 0, 0, 0);
        #pragma unroll
        for (int mi = 0; mi < 4; ++mi)
            af[mi] = *(const short8*)&As1[(wm * 64 + mi * 16 + lq) * 32 + lg * 8];
        #pragma unroll
        for (int ni = 0; ni < 4; ++ni)
            bfr[ni] = *(const short8*)&Bs1[(wn * 64 + ni * 16 + lq) * 32 + lg * 8];
        #pragma unroll
        for (int mi = 0; mi < 4; ++mi)
            #pragma unroll
            for (int ni = 0; ni < 4; ++ni)
                acc[mi][ni] = __builtin_amdgcn_mfma_f32_16x16x32_bf16(
                    af[mi], bfr[ni], acc[mi][ni], 0, 0, 0);
    }

    // ---------------- epilogue: bf16 scatter via LDS transpose ----------------
    __syncthreads();
    const int part = n0 >> 10;
    const int hh = ((n0 + wn * 64) & 1023) >> 6;
    const int mrow0 = m0 + wm * 64;
    const int bh = (mrow0 >> 11) * 16 + hh;
    const int tok0 = mrow0 & 2047;
    const float scl = (part == 0) ? 0.125f * 1.44269504089f : 1.0f;

    float bias4[4];
    #pragma unroll
    for (int ni = 0; ni < 4; ++ni)
        bias4[ni] = bias[n0 + wn * 64 + ni * 16 + lq];

    uint16_t* T = smem + w * 4608;                   // [64][72] bf16, wave-private
    if (part < 2) {
        #pragma unroll
        for (int mi = 0; mi < 4; ++mi)
            #pragma unroll
            for (int ni = 0; ni < 4; ++ni)
                #pragma unroll
                for (int r = 0; r < 4; ++r)
                    T[(mi * 16 + lg * 4 + r) * 72 + ni * 16 + lq] =
                        f2bf((acc[mi][ni][r] + bias4[ni]) * scl);
    } else {
        #pragma unroll
        for (int mi = 0; mi < 4; ++mi)
            #pragma unroll
            for (int ni = 0; ni < 4; ++ni)
                #pragma unroll
                for (int r = 0; r < 4; ++r)
                    T[(ni * 16 + lq) * 72 + mi * 16 + lg * 4 + r] =
                        f2bf(acc[mi][ni][r] + bias4[ni]);
    }

    const int a0 = l >> 3, b8 = (l & 7) * 8;
    #pragma unroll
    for (int i = 0; i < 8; ++i) {
        int a = i * 8 + a0;
        short8 u = *(short8*)&T[a * 72 + b8];
        uint16_t* p;
        if (part < 2) {
            uint16_t* dst = (part == 0) ? Qb : Kb;
            p = dst + ((size_t)bh * 2048 + tok0 + a) * 64 + b8;
        } else {
            p = Vt + ((size_t)bh * 64 + a) * 2048 + tok0 + b8;
        }
        *(short8*)p = u;
    }
}

// ======================= MFMA flash attention (64 q-rows/wave, kv-split) ========
// EXACT r19 structure (verified best: attn 57.4us, total 123.9us).
// 1024 blocks x 128 thr; block = 64 q-rows; wave w owns kv tiles kt===w (mod 2);
// blk = 31-(id>>5) heaviest-first; bh = id&31 (XCD K/V affinity); sub-pairs
// QK01 -> SM+PV01 -> QK23 -> K refill -> SM+PV23; exact 2-wave LDS merge.
__device__ __forceinline__ void loadK8(const uint16_t* kp, short8 (&d)[8]) {
    #pragma unroll
    for (int n = 0; n < 4; ++n) {
        d[2 * n]     = *(const short8*)(kp + n * 1024);
        d[2 * n + 1] = *(const short8*)(kp + n * 1024 + 32);
    }
}
__device__ __forceinline__ void loadV8(const uint16_t* vp, short8 (&d)[8]) {
    #pragma unroll
    for (int n = 0; n < 4; ++n) {
        d[2 * n]     = *(const short8*)(vp + n * 32768);
        d[2 * n + 1] = *(const short8*)(vp + n * 32768 + 32);
    }
}

#define DEFER_THR 11.5f   // ~8 nats in log2 units

__global__ __launch_bounds__(128) void attn_mfma(
    const uint16_t* __restrict__ Q, const uint16_t* __restrict__ K,
    const uint16_t* __restrict__ Vt, uint16_t* __restrict__ Y)
{
    const int id = blockIdx.x;
    const int bh = id & 31;               // id%8 -> stable XCD per bh group
    const int blk = 31 - (id >> 5);       // 64-row q-block, heaviest first
    const int qt = blk;                   // last kv tile index
    const int q0 = blk * 64;

    const int wv = threadIdx.x >> 6;      // kv-parity this wave owns
    const int lane = threadIdx.x & 63;
    const int lq = lane & 15;
    const int lg = lane >> 4;

    __shared__ __align__(16) uint16_t Pl[2][2][16][72];  // [wave][pair-slot]
    __shared__ float  My[64][68];                        // wave1 partial y (padded)
    __shared__ float2 Mml[64];                           // wave1 (m, lsum) per q-row

    const uint16_t* Kb = K + (size_t)bh * (2048 * 64);
    const uint16_t* Vb = Vt + (size_t)bh * (64 * 2048);
    const int b = bh >> 4, h = bh & 15;

    short8 qf[4][2];
    #pragma unroll
    for (int sub = 0; sub < 4; ++sub) {
        const uint16_t* qb = Q + ((size_t)bh * 2048 + q0 + sub * 16 + lq) * 64 + lg * 8;
        qf[sub][0] = *(const short8*)qb;
        qf[sub][1] = *(const short8*)(qb + 32);
    }

    f32x4 y[4][4] = {};
    float m[4]    = {-INFINITY, -INFINITY, -INFINITY, -INFINITY};
    float lsum[4] = {0.f, 0.f, 0.f, 0.f};

    const uint16_t* kp = Kb + ((size_t)(wv * 64 + lq)) * 64 + lg * 8;
    const uint16_t* vp = Vb + (size_t)lq * 2048 + wv * 64 + lg * 8;

    short8 kf[8], vv[8];

    // swapped QK^T for a sub-pair: z[p][n][r] = S[q0+(s0+p)*16+lq][kv0+n*16+lg*4+r]
    auto qkpair = [&](f32x4 (&z)[2][4], int s0) {
        __builtin_amdgcn_s_setprio(1);
        #pragma unroll
        for (int p = 0; p < 2; ++p)
            #pragma unroll
            for (int n = 0; n < 4; ++n) {
                f32x4 t = {};
                t = __builtin_amdgcn_mfma_f32_16x16x32_bf16(kf[2 * n], qf[s0 + p][0], t, 0, 0, 0);
                z[p][n] = __builtin_amdgcn_mfma_f32_16x16x32_bf16(kf[2 * n + 1], qf[s0 + p][1], t, 0, 0, 0);
            }
        __builtin_amdgcn_s_setprio(0);
    };

    auto smpv = [&](f32x4 (&z)[2][4], int s0, int kv0, bool domask) {
        if (domask) {
            #pragma unroll
            for (int p = 0; p < 2; ++p) {
                const int qrow = q0 + (s0 + p) * 16 + lq;
                #pragma unroll
                for (int n = 0; n < 4; ++n) {
                    const int kvb = kv0 + n * 16 + lg * 4;
                    #pragma unroll
                    for (int r = 0; r < 4; ++r)
                        if (kvb + r > qrow) z[p][n][r] = -INFINITY;
                }
            }
        }
        float mt[2];
        #pragma unroll
        for (int p = 0; p < 2; ++p) {
            float t = -INFINITY;
            #pragma unroll
            for (int n = 0; n < 4; ++n)
                #pragma unroll
                for (int r = 0; r < 4; ++r)
                    t = fmaxf(t, z[p][n][r]);
            mt[p] = t;
        }
        const float g = fmaxf(mt[0] - m[s0], mt[1] - m[s0 + 1]);
        const bool skip = __all(g <= DEFER_THR);
        if (!skip) {
            #pragma unroll
            for (int p = 0; p < 2; ++p) {
                const int s = s0 + p;
                float mf = fmaxf(mt[p], __shfl_xor(mt[p], 16));
                mf = fmaxf(mf, __shfl_xor(mf, 32));
                const float mn = fmaxf(m[s], mf);
                const float sc = exp2f(m[s] - mn);
                m[s] = mn;
                lsum[s] *= sc;
                float scy[4];
                #pragma unroll
                for (int r = 0; r < 4; ++r) scy[r] = __shfl(sc, lg * 4 + r);
                #pragma unroll
                for (int n = 0; n < 4; ++n)
                    #pragma unroll
                    for (int r = 0; r < 4; ++r)
                        y[s][n][r] *= scy[r];
            }
        }
        float ps[2] = {0.f, 0.f};
        #pragma unroll
        for (int p = 0; p < 2; ++p) {
            const int s = s0 + p;
            #pragma unroll
            for (int n = 0; n < 4; ++n) {
                float e0 = exp2f(z[p][n][0] - m[s]);
                float e1 = exp2f(z[p][n][1] - m[s]);
                float e2 = exp2f(z[p][n][2] - m[s]);
                float e3 = exp2f(z[p][n][3] - m[s]);
                ps[p] += (e0 + e1) + (e2 + e3);
                uint32_t p0, p1;
                asm("v_cvt_pk_bf16_f32 %0, %1, %2" : "=v"(p0) : "v"(e0), "v"(e1));
                asm("v_cvt_pk_bf16_f32 %0, %1, %2" : "=v"(p1) : "v"(e2), "v"(e3));
                uint2 u; u.x = p0; u.y = p1;
                *(uint2*)&Pl[wv][p][lq][n * 16 + lg * 4] = u;
            }
        }
        lsum[s0] += ps[0];
        lsum[s0 + 1] += ps[1];

        short8 pa[2][2];
        #pragma unroll
        for (int p = 0; p < 2; ++p) {
            pa[p][0] = *(short8*)&Pl[wv][p][lq][lg * 8];
            pa[p][1] = *(short8*)&Pl[wv][p][lq][lg * 8 + 32];
        }
        __builtin_amdgcn_s_setprio(1);
        #pragma unroll
        for (int p = 0; p < 2; ++p) {
            const int s = s0 + p;
            #pragma unroll
            for (int n = 0; n < 4; ++n) {
                y[s][n] = __builtin_amdgcn_mfma_f32_16x16x32_bf16(pa[p][0], vv[2 * n], y[s][n], 0, 0, 0);
                y[s][n] = __builtin_amdgcn_mfma_f32_16x16x32_bf16(pa[p][1], vv[2 * n + 1], y[s][n], 0, 0, 0);
            }
        }
        __builtin_amdgcn_s_setprio(0);
    };

    if (wv <= qt) {
        loadK8(kp, kf);
        int kt = wv;
        while (true) {
            const bool last = (kt + 2 > qt);
            const bool domask = (kt == qt);
            const int kv0 = kt * 64;
            loadV8(vp, vv);
            f32x4 z[2][4];
            qkpair(z, 0);
            smpv(z, 0, kv0, domask);
            qkpair(z, 2);
            if (!last) loadK8(kp + 8192, kf);   // consumed by both QK phases
            smpv(z, 2, kv0, domask);
            if (last) break;
            kp += 8192; vp += 128; kt += 2;
        }
    }

    // ---- reduce per-lane lsum across lg groups ----
    float ls[4];
    #pragma unroll
    for (int s = 0; s < 4; ++s) {
        float t = lsum[s];
        t += __shfl_xor(t, 16);
        t += __shfl_xor(t, 32);
        ls[s] = t;
    }

    // ---- merge: wave1 posts partials; wave0 combines + writes ----
    if (wv == 1) {
        #pragma unroll
        for (int s = 0; s < 4; ++s) {
            #pragma unroll
            for (int n = 0; n < 4; ++n)
                #pragma unroll
                for (int r = 0; r < 4; ++r)
                    My[s * 16 + lg * 4 + r][n * 16 + lq] = y[s][n][r];
            if (lg == 0) Mml[s * 16 + lq] = make_float2(m[s], ls[s]);
        }
    }
    __syncthreads();
    if (wv == 0) {
        #pragma unroll
        for (int s = 0; s < 4; ++s) {
            float2 o = Mml[s * 16 + lq];
            const float m1 = o.x, l1 = o.y;
            const float mx = fmaxf(m[s], m1);
            const float w0 = exp2f(m[s] - mx);
            const float w1 = exp2f(m1 - mx);
            const float inv = 1.0f / (ls[s] * w0 + l1 * w1);
            const float f0 = w0 * inv, f1 = w1 * inv;
            float f0r[4], f1r[4];
            #pragma unroll
            for (int r = 0; r < 4; ++r) {
                f0r[r] = __shfl(f0, lg * 4 + r);
                f1r[r] = __shfl(f1, lg * 4 + r);
            }
            #pragma unroll
            for (int r = 0; r < 4; ++r) {
                int token = b * 2048 + q0 + s * 16 + lg * 4 + r;
                uint16_t* yrow = Y + (size_t)token * 1024 + h * 64;
                #pragma unroll
                for (int n = 0; n < 4; ++n) {
                    float val = y[s][n][r] * f0r[r] +
                                My[s * 16 + lg * 4 + r][n * 16 + lq] * f1r[r];
                    yrow[n * 16 + lq] = f2bf(val);
                }
            }
        }
    }
}

// ======================= output projection (MFMA, fp32 out) =======================
// out[4096,1024] = Y(bf16) @ Wo(bf16)^T + bo. BK=64 + XCD column affinity.
__global__ __launch_bounds__(256) void gemm_proj(
    const uint16_t* __restrict__ Yin, const uint16_t* __restrict__ W,
    const float* __restrict__ bias, float* __restrict__ out)
{
    __shared__ __align__(16) uint16_t smem[16384];   // 4 x [128][32] = 32 KB
    uint16_t* As0 = smem;
    uint16_t* As1 = smem + 4096;
    uint16_t* Bs0 = smem + 8192;
    uint16_t* Bs1 = smem + 12288;

    const int tid = threadIdx.x;
    const int w = tid >> 6, l = tid & 63;
    const int lq = l & 15, lg = l >> 4;
    const int wm = w >> 1, wn = w & 1;

    const int flat = blockIdx.x + blockIdx.y * 8;
    const int n0 = (flat & 7) * 128;
    const int m0 = (flat >> 3) * 128;

    f32x4 acc[4][4] = {};

    for (int k0 = 0; k0 < 1024; k0 += 64) {
        __syncthreads();
        #pragma unroll
        for (int j = 0; j < 2; ++j) {
            const int c = (j * 4 + w) * 64 + l;
            const size_t ra = (size_t)(m0 + (c >> 2)) * 1024 + k0 + (c & 3) * 8;
            const size_t rb = (size_t)(n0 + (c >> 2)) * 1024 + k0 + (c & 3) * 8;
            load_lds16(Yin + ra,      As0 + (j * 4 + w) * 512);
            load_lds16(Yin + ra + 32, As1 + (j * 4 + w) * 512);
            load_lds16(W + rb,        Bs0 + (j * 4 + w) * 512);
            load_lds16(W + rb + 32,   Bs1 + (j * 4 + w) * 512);
        }
        __syncthreads();
        short8 af[4], bfr[4];
        #pragma unroll
        for (int mi = 0; mi < 4; ++mi)
            af[mi] = *(const short8*)&As0[(wm * 64 + mi * 16 + lq) * 32 + lg * 8];
        #pragma unroll
        for (int ni = 0; ni < 4; ++ni)
            bfr[ni] = *(const short8*)&Bs0[(wn * 64 + ni * 16 + lq) * 32 + lg * 8];
        #pragma unroll
        for (int mi = 0; mi < 4; ++mi)
            #pragma unroll
            for (int ni = 0; ni < 4; ++ni)
                acc[mi][ni] = __builtin_amdgcn_mfma_f32_16x16x32_bf16(
                    af[mi], bfr[ni], acc[mi][ni], 0, 0, 0);
        #pragma unroll
        for (int mi = 0; mi < 4; ++mi)
            af[mi] = *(const short8*)&As1[(wm * 64 + mi * 16 + lq) * 32 + lg * 8];
        #pragma unroll
        for (int ni = 0; ni < 4; ++ni)
            bfr[ni] = *(const short8*)&Bs1[(wn * 64 + ni * 16 + lq) * 32 + lg * 8];
        #pragma unroll
        for (int mi = 0; mi < 4; ++mi)
            #pragma unroll
            for (int ni = 0; ni < 4; ++ni)
                acc[mi][ni] = __builtin_amdgcn_mfma_f32_16x16x32_bf16(
                    af[mi], bfr[ni], acc[mi][ni], 0, 0, 0);
    }

    const int mrow0 = m0 + wm * 64;
    const int ncol0 = n0 + wn * 64;
    float bias4[4];
    #pragma unroll
    for (int ni = 0; ni < 4; ++ni)
        bias4[ni] = bias[ncol0 + ni * 16 + lq];

    #pragma unroll
    for (int mi = 0; mi < 4; ++mi)
        #pragma unroll
        for (int r = 0; r < 4; ++r) {
            const size_t rowoff = (size_t)(mrow0 + mi * 16 + lg * 4 + r) * 1024;
            #pragma unroll
            for (int ni = 0; ni < 4; ++ni)
                out[rowoff + ncol0 + ni * 16 + lq] = acc[mi][ni][r] + bias4[ni];
        }
}

// ======================= launcher =======================

extern "C" void kernel_launch(void* const* d_in, const int* in_sizes, int n_in,
                              void* d_out, int out_size, void* d_ws, size_t ws_size,
                              hipStream_t stream) {
    const float* x    = (const float*)d_in[0];
    // d_in[1] (causal mask) applied structurally.
    const float* Wqkv = (const float*)d_in[2];
    const float* bqkv = (const float*)d_in[3];
    const float* Wo   = (const float*)d_in[4];
    const float* bo   = (const float*)d_in[5];

    const size_t QK = (size_t)BB * HH * NN * SS;  // 4,194,304

    uint16_t* Xb  = (uint16_t*)d_ws;
    uint16_t* Wqb = Xb + XE;
    uint16_t* Wob = Wqb + WQE;
    uint16_t* Qb  = Wob + WOE;
    uint16_t* Kb  = Qb + QK;
    uint16_t* Vt  = Kb + QK;
    uint16_t* Yb  = Vt + QK;

    cvt_all<<<(XE + WQE + WOE) / 8 / 256, 256, 0, stream>>>(x, Wqkv, Wo, Xb);
    gemm_qkv<<<dim3(24, 32), 256, 0, stream>>>(Xb, Wqb, bqkv, Qb, Kb, Vt);
    attn_mfma<<<1024, 128, 0, stream>>>(Qb, Kb, Vt, Yb);
    gemm_proj<<<dim3(8, 32), 256, 0, stream>>>(Yb, Wob, bo, (float*)d_out);
}